// Round 4
// baseline (1155.469 us; speedup 1.0000x reference)
//
#include <hip/hip_runtime.h>
#include <math.h>

#define B_DIM 16
#define A_DIM 1024
#define V_DIM 512
#define D_DIM 512
#define NEGV  (-1e30f)

typedef short bf16x8 __attribute__((ext_vector_type(8)));
typedef float floatx4 __attribute__((ext_vector_type(4)));

// ---------------------------------------------------------------------------
// fp32 -> (hi,lo) bf16 split of 8 values. hi = truncate-to-bf16(x),
// lo = truncate-to-bf16(x - hi). Residual ~2^-16 relative.
// ---------------------------------------------------------------------------
__device__ __forceinline__ void cvt_split8(const float v[8], bf16x8* h, bf16x8* l)
{
    #pragma unroll
    for (int e = 0; e < 8; ++e) {
        unsigned u = __float_as_uint(v[e]);
        float hf = __uint_as_float(u & 0xffff0000u);
        (*h)[e] = (short)(u >> 16);
        (*l)[e] = (short)(__float_as_uint(v[e] - hf) >> 16);
    }
}

// ---------------------------------------------------------------------------
// Split-bf16 MFMA NT GEMM: C[M,N] = A[M,K]*B[N,K]^T (+bias), batched strides.
// Block tile 128x128, BK=32, 256 threads (4 waves, 2x2 wave grid, 64x64/wave).
// LDS holds hi/lo bf16 tiles in MFMA fragment order (lane-major 16B units).
// If SOFTMAX: A[m][k] = exp(sim[m][k]-rmax[m])*rinv[m] computed while staging.
// ---------------------------------------------------------------------------
template <bool SOFTMAX>
__global__ __launch_bounds__(256, 2) void gemm_mfma_kernel(
    const float* __restrict__ Ag, const float* __restrict__ Bg,
    const float* __restrict__ bias, float* __restrict__ Cg,
    const float* __restrict__ rmax, const float* __restrict__ rinv,
    int M, int N, int K, size_t sA, size_t sB, size_t sC)
{
    __shared__ __align__(16) short sAh[8*64*8];   // 8 m-tiles x 64 lanes x 8 bf16
    __shared__ __align__(16) short sAl[8*64*8];
    __shared__ __align__(16) short sBh[8*64*8];
    __shared__ __align__(16) short sBl[8*64*8];

    const int bz = blockIdx.z;
    const float* Ab = Ag + (size_t)bz * sA;
    const float* Bb = Bg + (size_t)bz * sB;
    float*       Cb = Cg + (size_t)bz * sC;

    const int m0 = blockIdx.y * 128;
    const int n0 = blockIdx.x * 128;
    const int tid  = threadIdx.x;
    const int lane = tid & 63;
    const int w    = tid >> 6;
    const int wy   = w >> 1, wx = w & 1;

    // staging units: (row r, quad q); thread handles units tid and tid+256.
    const int r0 = tid >> 2, q0 = tid & 3;     // rows 0..63
    const int r1 = r0 + 64;                    // rows 64..127

    float rm0 = 0.f, ri0 = 0.f, rm1 = 0.f, ri1 = 0.f;
    if (SOFTMAX) {
        rm0 = rmax[(size_t)bz*A_DIM + m0 + r0]; ri0 = rinv[(size_t)bz*A_DIM + m0 + r0];
        rm1 = rmax[(size_t)bz*A_DIM + m0 + r1]; ri1 = rinv[(size_t)bz*A_DIM + m0 + r1];
    }
    const float L2E = 1.44269504f;

    floatx4 acc[4][4];
    #pragma unroll
    for (int i = 0; i < 4; ++i)
        #pragma unroll
        for (int j = 0; j < 4; ++j) acc[i][j] = (floatx4){0.f, 0.f, 0.f, 0.f};

    for (int k0 = 0; k0 < K; k0 += 32) {
        // ---- global loads (regs) ----
        const float* pa0 = Ab + (size_t)(m0 + r0) * K + k0 + q0*8;
        const float* pa1 = Ab + (size_t)(m0 + r1) * K + k0 + q0*8;
        const float* pb0 = Bb + (size_t)(n0 + r0) * K + k0 + q0*8;
        const float* pb1 = Bb + (size_t)(n0 + r1) * K + k0 + q0*8;
        float4 a00 = *(const float4*)(pa0), a01 = *(const float4*)(pa0 + 4);
        float4 a10 = *(const float4*)(pa1), a11 = *(const float4*)(pa1 + 4);
        float4 b00 = *(const float4*)(pb0), b01 = *(const float4*)(pb0 + 4);
        float4 b10 = *(const float4*)(pb1), b11 = *(const float4*)(pb1 + 4);

        float va0[8] = {a00.x,a00.y,a00.z,a00.w,a01.x,a01.y,a01.z,a01.w};
        float va1[8] = {a10.x,a10.y,a10.z,a10.w,a11.x,a11.y,a11.z,a11.w};
        float vb0[8] = {b00.x,b00.y,b00.z,b00.w,b01.x,b01.y,b01.z,b01.w};
        float vb1[8] = {b10.x,b10.y,b10.z,b10.w,b11.x,b11.y,b11.z,b11.w};
        if (SOFTMAX) {
            #pragma unroll
            for (int e = 0; e < 8; ++e) {
                va0[e] = exp2f((va0[e] - rm0) * L2E) * ri0;
                va1[e] = exp2f((va1[e] - rm1) * L2E) * ri1;
            }
        }
        bf16x8 ah0, al0, ah1, al1, bh0, bl0, bh1, bl1;
        cvt_split8(va0, &ah0, &al0); cvt_split8(va1, &ah1, &al1);
        cvt_split8(vb0, &bh0, &bl0); cvt_split8(vb1, &bh1, &bl1);

        __syncthreads();
        // fragment-order LDS: off = (tile*64 + q*16 + (row&15)) * 8 shorts
        const int oa0 = ((r0 >> 4)*64 + q0*16 + (r0 & 15)) * 8;
        const int oa1 = ((r1 >> 4)*64 + q0*16 + (r1 & 15)) * 8;
        *(bf16x8*)&sAh[oa0] = ah0; *(bf16x8*)&sAl[oa0] = al0;
        *(bf16x8*)&sAh[oa1] = ah1; *(bf16x8*)&sAl[oa1] = al1;
        *(bf16x8*)&sBh[oa0] = bh0; *(bf16x8*)&sBl[oa0] = bl0;
        *(bf16x8*)&sBh[oa1] = bh1; *(bf16x8*)&sBl[oa1] = bl1;
        __syncthreads();

        bf16x8 fah[4], fal[4], fbh[4], fbl[4];
        #pragma unroll
        for (int t = 0; t < 4; ++t) {
            const int offa = ((wy*4 + t)*64 + lane) * 8;
            const int offb = ((wx*4 + t)*64 + lane) * 8;
            fah[t] = *(const bf16x8*)&sAh[offa];
            fal[t] = *(const bf16x8*)&sAl[offa];
            fbh[t] = *(const bf16x8*)&sBh[offb];
            fbl[t] = *(const bf16x8*)&sBl[offb];
        }
        #pragma unroll
        for (int i = 0; i < 4; ++i)
            #pragma unroll
            for (int j = 0; j < 4; ++j) {
                acc[i][j] = __builtin_amdgcn_mfma_f32_16x16x32_bf16(fah[i], fbh[j], acc[i][j], 0, 0, 0);
                acc[i][j] = __builtin_amdgcn_mfma_f32_16x16x32_bf16(fah[i], fbl[j], acc[i][j], 0, 0, 0);
                acc[i][j] = __builtin_amdgcn_mfma_f32_16x16x32_bf16(fal[i], fbh[j], acc[i][j], 0, 0, 0);
            }
    }

    // epilogue: D row = quad*4 + reg, col = lane&15  [m89/m91-verified layout]
    const int q = lane >> 4, c = lane & 15;
    #pragma unroll
    for (int i = 0; i < 4; ++i)
        #pragma unroll
        for (int j = 0; j < 4; ++j) {
            const int n = n0 + (wx*4 + j)*16 + c;
            const float bv = bias ? bias[n] : 0.f;
            #pragma unroll
            for (int r = 0; r < 4; ++r) {
                const int m = m0 + (wy*4 + i)*16 + q*4 + r;
                Cb[(size_t)m * N + n] = acc[i][j][r] + bv;
            }
        }
}

// ---------------------------------------------------------------------------
// Batched 32x32 transpose: video[b][v][d] -> vT[b][d][v].
// ---------------------------------------------------------------------------
__global__ __launch_bounds__(256) void transpose_kernel(
    const float* __restrict__ in, float* __restrict__ out)
{
    __shared__ float t[32][33];
    const int b = blockIdx.z;
    const int v0 = blockIdx.y * 32, d0 = blockIdx.x * 32;
    const int x = threadIdx.x & 31, y0 = (threadIdx.x >> 5) * 4;
    const float* I = in  + ((size_t)b * V_DIM + v0) * D_DIM + d0;
    #pragma unroll
    for (int r = 0; r < 4; ++r) t[y0 + r][x] = I[(size_t)(y0 + r) * D_DIM + x];
    __syncthreads();
    float* O = out + ((size_t)b * D_DIM + d0) * V_DIM + v0;
    #pragma unroll
    for (int r = 0; r < 4; ++r) O[(size_t)(y0 + r) * V_DIM + x] = t[x][y0 + r];
}

// ---------------------------------------------------------------------------
// Row L2-normalize in place. One wave/row.
// ---------------------------------------------------------------------------
__global__ __launch_bounds__(256) void rownorm_kernel(float* __restrict__ x)
{
    const int wave = threadIdx.x >> 6;
    const int lane = threadIdx.x & 63;
    const size_t r = (size_t)blockIdx.x * 4 + wave;
    float* p = x + r * D_DIM;
    float4 u = *(float4*)(p + lane*4);
    float4 w = *(float4*)(p + 256 + lane*4);
    float ss = u.x*u.x + u.y*u.y + u.z*u.z + u.w*u.w
             + w.x*w.x + w.y*w.y + w.z*w.z + w.w*w.w;
    #pragma unroll
    for (int m = 1; m < 64; m <<= 1) ss += __shfl_xor(ss, m, 64);
    const float inv = 1.0f / fmaxf(sqrtf(ss), 1e-12f);
    u.x*=inv; u.y*=inv; u.z*=inv; u.w*=inv;
    w.x*=inv; w.y*=inv; w.z*=inv; w.w*=inv;
    *(float4*)(p + lane*4)       = u;
    *(float4*)(p + 256 + lane*4) = w;
}

// ---------------------------------------------------------------------------
// Softmax row stats: rmax[r], rinv[r] = 1/sum(exp(s-max)).
// ---------------------------------------------------------------------------
__global__ __launch_bounds__(256) void rowstat_kernel(
    const float* __restrict__ sim, float* __restrict__ rmax, float* __restrict__ rinv)
{
    const int wave = threadIdx.x >> 6;
    const int lane = threadIdx.x & 63;
    const size_t r = (size_t)blockIdx.x * 4 + wave;
    const float* p = sim + r * V_DIM;
    float4 u = *(const float4*)(p + lane*4);
    float4 w = *(const float4*)(p + 256 + lane*4);
    float m = fmaxf(fmaxf(fmaxf(u.x,u.y), fmaxf(u.z,u.w)),
                    fmaxf(fmaxf(w.x,w.y), fmaxf(w.z,w.w)));
    #pragma unroll
    for (int s = 1; s < 64; s <<= 1) m = fmaxf(m, __shfl_xor(m, s, 64));
    float e = __expf(u.x-m)+__expf(u.y-m)+__expf(u.z-m)+__expf(u.w-m)
            + __expf(w.x-m)+__expf(w.y-m)+__expf(w.z-m)+__expf(w.w-m);
    #pragma unroll
    for (int s = 1; s < 64; s <<= 1) e += __shfl_xor(e, s, 64);
    if (lane == 0) { rmax[r] = m; rinv[r] = 1.0f / e; }
}

// ---------------------------------------------------------------------------
// DPP helpers (wave64) — verified in R2/R3.
// ---------------------------------------------------------------------------
template <int CTRL, int RMASK>
__device__ __forceinline__ float fdpp(float oldv, float src) {
    int r = __builtin_amdgcn_update_dpp(
        __float_as_int(oldv), __float_as_int(src), CTRL, RMASK, 0xF, false);
    return __int_as_float(r);
}

__device__ __forceinline__ float wave_incl_add(float x) {
    x += fdpp<0x111, 0xF>(0.f, x);
    x += fdpp<0x112, 0xF>(0.f, x);
    x += fdpp<0x114, 0xF>(0.f, x);
    x += fdpp<0x118, 0xF>(0.f, x);
    x += fdpp<0x142, 0xA>(0.f, x);
    x += fdpp<0x143, 0xC>(0.f, x);
    return x;
}

// ---------------------------------------------------------------------------
// In-place inclusive prefix sum along each sim row (1 wave per row).
// ---------------------------------------------------------------------------
__global__ __launch_bounds__(256) void rowpsum_kernel(float* __restrict__ sim)
{
    const int wave = threadIdx.x >> 6;
    const int lane = threadIdx.x & 63;
    const size_t r = (size_t)blockIdx.x * 4 + wave;
    float* p = sim + r * V_DIM + lane * 8;
    float4 u = *(float4*)p;
    float4 w = *(float4*)(p + 4);
    float s[8] = {u.x,u.y,u.z,u.w,w.x,w.y,w.z,w.w};
    #pragma unroll
    for (int k = 1; k < 8; ++k) s[k] += s[k-1];
    float excl = fdpp<0x138, 0xF>(0.f, wave_incl_add(s[7]));
    #pragma unroll
    for (int k = 0; k < 8; ++k) s[k] += excl;
    *(float4*)p       = make_float4(s[0], s[1], s[2], s[3]);
    *(float4*)(p + 4) = make_float4(s[4], s[5], s[6], s[7]);
}

// ---------------------------------------------------------------------------
// DTW on pre-summed rows, 4 batches interleaved per wave (ILP to hide VALU
// latency at 1-wave occupancy). dp_j = P_j + max_{k<=j}(m_k - P_{k-1}).
// ---------------------------------------------------------------------------
__device__ __forceinline__ void dtw_row4(const float P[4][8], float dp[4][8], float bnd)
{
    float Pexcl[4], prevlast[4], q[4][8], t[4];
    #pragma unroll
    for (int c = 0; c < 4; ++c) Pexcl[c]    = fdpp<0x138, 0xF>(0.0f, P[c][7]);
    #pragma unroll
    for (int c = 0; c < 4; ++c) prevlast[c] = fdpp<0x138, 0xF>(bnd,  dp[c][7]);
    #pragma unroll
    for (int c = 0; c < 4; ++c) q[c][0] = fmaxf(dp[c][0], prevlast[c]) - Pexcl[c];
    #pragma unroll
    for (int k = 1; k < 8; ++k)
        #pragma unroll
        for (int c = 0; c < 4; ++c) q[c][k] = fmaxf(dp[c][k], dp[c][k-1]) - P[c][k-1];
    // serial in-lane max scan (4 independent chains interleave)
    #pragma unroll
    for (int k = 1; k < 8; ++k)
        #pragma unroll
        for (int c = 0; c < 4; ++c) q[c][k] = fmaxf(q[c][k], q[c][k-1]);
    #pragma unroll
    for (int c = 0; c < 4; ++c) t[c] = q[c][7];
    #pragma unroll
    for (int c = 0; c < 4; ++c) t[c] = fmaxf(t[c], fdpp<0x111, 0xF>(NEGV, t[c]));
    #pragma unroll
    for (int c = 0; c < 4; ++c) t[c] = fmaxf(t[c], fdpp<0x112, 0xF>(NEGV, t[c]));
    #pragma unroll
    for (int c = 0; c < 4; ++c) t[c] = fmaxf(t[c], fdpp<0x114, 0xF>(NEGV, t[c]));
    #pragma unroll
    for (int c = 0; c < 4; ++c) t[c] = fmaxf(t[c], fdpp<0x118, 0xF>(NEGV, t[c]));
    #pragma unroll
    for (int c = 0; c < 4; ++c) t[c] = fmaxf(t[c], fdpp<0x142, 0xA>(NEGV, t[c]));
    #pragma unroll
    for (int c = 0; c < 4; ++c) t[c] = fmaxf(t[c], fdpp<0x143, 0xC>(NEGV, t[c]));
    float Qex[4];
    #pragma unroll
    for (int c = 0; c < 4; ++c) Qex[c] = fdpp<0x138, 0xF>(NEGV, t[c]);
    #pragma unroll
    for (int k = 0; k < 8; ++k)
        #pragma unroll
        for (int c = 0; c < 4; ++c) dp[c][k] = P[c][k] + fmaxf(Qex[c], q[c][k]);
}

__global__ __launch_bounds__(64) void dtw_scan4_kernel(
    const float* __restrict__ psum, float* __restrict__ score)
{
    const int b0 = blockIdx.x * 4;
    const int lane = threadIdx.x;
    const float* S[4];
    #pragma unroll
    for (int c = 0; c < 4; ++c)
        S[c] = psum + (size_t)(b0 + c) * A_DIM * V_DIM + lane * 8;

    float dp[4][8];
    #pragma unroll
    for (int c = 0; c < 4; ++c)
        #pragma unroll
        for (int k = 0; k < 8; ++k) dp[c][k] = NEGV;

    // depth-2 double-buffer prefetch per batch
    float4 pa[4][2], pb[4][2];
    #pragma unroll
    for (int c = 0; c < 4; ++c)
        #pragma unroll
        for (int s = 0; s < 2; ++s) {
            pa[c][s] = *(const float4*)(S[c] + (size_t)s * V_DIM);
            pb[c][s] = *(const float4*)(S[c] + (size_t)s * V_DIM + 4);
        }

    for (int i0 = 1; i0 <= A_DIM; i0 += 2) {
        #pragma unroll
        for (int s = 0; s < 2; ++s) {
            const int i = i0 + s;
            float P[4][8];
            #pragma unroll
            for (int c = 0; c < 4; ++c) {
                P[c][0]=pa[c][s].x; P[c][1]=pa[c][s].y; P[c][2]=pa[c][s].z; P[c][3]=pa[c][s].w;
                P[c][4]=pb[c][s].x; P[c][5]=pb[c][s].y; P[c][6]=pb[c][s].z; P[c][7]=pb[c][s].w;
            }
            if (i + 2 <= A_DIM) {
                #pragma unroll
                for (int c = 0; c < 4; ++c) {
                    pa[c][s] = *(const float4*)(S[c] + (size_t)(i + 1) * V_DIM);
                    pb[c][s] = *(const float4*)(S[c] + (size_t)(i + 1) * V_DIM + 4);
                }
            }
            dtw_row4(P, dp, (i == 1) ? 0.0f : NEGV);
        }
    }
    if (lane == 63) {
        #pragma unroll
        for (int c = 0; c < 4; ++c) score[b0 + c] = dp[c][7];
    }
}

// ---------------------------------------------------------------------------
extern "C" void kernel_launch(void* const* d_in, const int* in_sizes, int n_in,
                              void* d_out, int out_size, void* d_ws, size_t ws_size,
                              hipStream_t stream)
{
    const float* audio = (const float*)d_in[0];   // [16,1024,512]
    const float* video = (const float*)d_in[1];   // [16, 512,512]
    const float* W     = (const float*)d_in[2];   // [512,512]
    const float* bias  = (const float*)d_in[3];   // [512]

    float* out_aligned = (float*)d_out;                                   // [16,1024,512]
    float* out_score   = (float*)d_out + (size_t)B_DIM * A_DIM * D_DIM;   // [16]

    float* ws   = (float*)d_ws;
    float* a_n  = ws;                                        // 16384 x 512
    float* v_n  = a_n  + (size_t)B_DIM * A_DIM * D_DIM;      //  8192 x 512 (later reused as vT)
    float* sim  = v_n  + (size_t)B_DIM * V_DIM * D_DIM;      // 16 x 1024 x 512
    float* rmax = sim  + (size_t)B_DIM * A_DIM * V_DIM;      // 16384
    float* rinv = rmax + (size_t)B_DIM * A_DIM;              // 16384
    float* vT   = v_n;                                       // [16][512 d][512 v]

    // 1) projections: X @ W^T + b  (split-bf16 MFMA)
    gemm_mfma_kernel<false><<<dim3(D_DIM/128, (B_DIM*A_DIM)/128, 1), dim3(256), 0, stream>>>(
        audio, W, bias, a_n, nullptr, nullptr, B_DIM*A_DIM, D_DIM, D_DIM, 0, 0, 0);
    gemm_mfma_kernel<false><<<dim3(D_DIM/128, (B_DIM*V_DIM)/128, 1), dim3(256), 0, stream>>>(
        video, W, bias, v_n, nullptr, nullptr, B_DIM*V_DIM, D_DIM, D_DIM, 0, 0, 0);

    // 2) L2-normalize all projected rows (a_n, v_n contiguous)
    rownorm_kernel<<<dim3((B_DIM*(A_DIM+V_DIM))/4), dim3(256), 0, stream>>>(a_n);

    // 3) sim[b] = a_n[b] @ v_n[b]^T
    gemm_mfma_kernel<false><<<dim3(V_DIM/128, A_DIM/128, B_DIM), dim3(256), 0, stream>>>(
        a_n, v_n, nullptr, sim, nullptr, nullptr, A_DIM, V_DIM, D_DIM,
        (size_t)A_DIM*D_DIM, (size_t)V_DIM*D_DIM, (size_t)A_DIM*V_DIM);

    // 4) softmax row stats
    rowstat_kernel<<<dim3((B_DIM*A_DIM)/4), dim3(256), 0, stream>>>(sim, rmax, rinv);

    // 5) v_n is dead now -> transpose video into it for an NT PV GEMM
    transpose_kernel<<<dim3(D_DIM/32, V_DIM/32, B_DIM), dim3(256), 0, stream>>>(video, vT);

    // 6) aligned = softmax(sim) @ video  ==  P[A,V] * vT[D,V]^T
    gemm_mfma_kernel<true><<<dim3(D_DIM/128, A_DIM/128, B_DIM), dim3(256), 0, stream>>>(
        sim, vT, nullptr, out_aligned, rmax, rinv, A_DIM, D_DIM, V_DIM,
        (size_t)A_DIM*V_DIM, (size_t)V_DIM*D_DIM, (size_t)A_DIM*D_DIM);

    // 7) in-place row prefix sums of sim (raw sim fully consumed)
    rowpsum_kernel<<<dim3((B_DIM*A_DIM)/4), dim3(256), 0, stream>>>(sim);

    // 8) DTW alignment score, 4 batches per wave
    dtw_scan4_kernel<<<dim3(B_DIM/4), dim3(64), 0, stream>>>(sim, out_score);
}

// Round 5
// 485.981 us; speedup vs baseline: 2.3776x; 2.3776x over previous
//
#include <hip/hip_runtime.h>
#include <math.h>

#define B_DIM 16
#define A_DIM 1024
#define V_DIM 512
#define D_DIM 512
#define NEGV  (-1e30f)

typedef short bf16x8 __attribute__((ext_vector_type(8)));
typedef float floatx4 __attribute__((ext_vector_type(4)));

// ---------------------------------------------------------------------------
// fp32 -> (hi,lo) bf16 split of 8 values. hi = truncate-to-bf16(x),
// lo = truncate-to-bf16(x - hi). Residual ~2^-16 relative.
// ---------------------------------------------------------------------------
__device__ __forceinline__ void cvt_split8(const float v[8], bf16x8* h, bf16x8* l)
{
    #pragma unroll
    for (int e = 0; e < 8; ++e) {
        unsigned u = __float_as_uint(v[e]);
        float hf = __uint_as_float(u & 0xffff0000u);
        (*h)[e] = (short)(u >> 16);
        (*l)[e] = (short)(__float_as_uint(v[e] - hf) >> 16);
    }
}

// ---------------------------------------------------------------------------
// Split-bf16 MFMA NT GEMM: C[M,N] = A[M,K]*B[N,K]^T (+bias), batched strides.
// Block tile 128x128, BK=32, 256 threads (4 waves, 2x2 wave grid, 64x64/wave).
// ---------------------------------------------------------------------------
template <bool SOFTMAX>
__global__ __launch_bounds__(256, 2) void gemm_mfma_kernel(
    const float* __restrict__ Ag, const float* __restrict__ Bg,
    const float* __restrict__ bias, float* __restrict__ Cg,
    const float* __restrict__ rmax, const float* __restrict__ rinv,
    int M, int N, int K, size_t sA, size_t sB, size_t sC)
{
    __shared__ __align__(16) short sAh[8*64*8];
    __shared__ __align__(16) short sAl[8*64*8];
    __shared__ __align__(16) short sBh[8*64*8];
    __shared__ __align__(16) short sBl[8*64*8];

    const int bz = blockIdx.z;
    const float* Ab = Ag + (size_t)bz * sA;
    const float* Bb = Bg + (size_t)bz * sB;
    float*       Cb = Cg + (size_t)bz * sC;

    const int m0 = blockIdx.y * 128;
    const int n0 = blockIdx.x * 128;
    const int tid  = threadIdx.x;
    const int lane = tid & 63;
    const int w    = tid >> 6;
    const int wy   = w >> 1, wx = w & 1;

    const int r0 = tid >> 2, q0 = tid & 3;
    const int r1 = r0 + 64;

    float rm0 = 0.f, ri0 = 0.f, rm1 = 0.f, ri1 = 0.f;
    if (SOFTMAX) {
        rm0 = rmax[(size_t)bz*A_DIM + m0 + r0]; ri0 = rinv[(size_t)bz*A_DIM + m0 + r0];
        rm1 = rmax[(size_t)bz*A_DIM + m0 + r1]; ri1 = rinv[(size_t)bz*A_DIM + m0 + r1];
    }
    const float L2E = 1.44269504f;

    floatx4 acc[4][4];
    #pragma unroll
    for (int i = 0; i < 4; ++i)
        #pragma unroll
        for (int j = 0; j < 4; ++j) acc[i][j] = (floatx4){0.f, 0.f, 0.f, 0.f};

    for (int k0 = 0; k0 < K; k0 += 32) {
        const float* pa0 = Ab + (size_t)(m0 + r0) * K + k0 + q0*8;
        const float* pa1 = Ab + (size_t)(m0 + r1) * K + k0 + q0*8;
        const float* pb0 = Bb + (size_t)(n0 + r0) * K + k0 + q0*8;
        const float* pb1 = Bb + (size_t)(n0 + r1) * K + k0 + q0*8;
        float4 a00 = *(const float4*)(pa0), a01 = *(const float4*)(pa0 + 4);
        float4 a10 = *(const float4*)(pa1), a11 = *(const float4*)(pa1 + 4);
        float4 b00 = *(const float4*)(pb0), b01 = *(const float4*)(pb0 + 4);
        float4 b10 = *(const float4*)(pb1), b11 = *(const float4*)(pb1 + 4);

        float va0[8] = {a00.x,a00.y,a00.z,a00.w,a01.x,a01.y,a01.z,a01.w};
        float va1[8] = {a10.x,a10.y,a10.z,a10.w,a11.x,a11.y,a11.z,a11.w};
        float vb0[8] = {b00.x,b00.y,b00.z,b00.w,b01.x,b01.y,b01.z,b01.w};
        float vb1[8] = {b10.x,b10.y,b10.z,b10.w,b11.x,b11.y,b11.z,b11.w};
        if (SOFTMAX) {
            #pragma unroll
            for (int e = 0; e < 8; ++e) {
                va0[e] = exp2f((va0[e] - rm0) * L2E) * ri0;
                va1[e] = exp2f((va1[e] - rm1) * L2E) * ri1;
            }
        }
        bf16x8 ah0, al0, ah1, al1, bh0, bl0, bh1, bl1;
        cvt_split8(va0, &ah0, &al0); cvt_split8(va1, &ah1, &al1);
        cvt_split8(vb0, &bh0, &bl0); cvt_split8(vb1, &bh1, &bl1);

        __syncthreads();
        const int oa0 = ((r0 >> 4)*64 + q0*16 + (r0 & 15)) * 8;
        const int oa1 = ((r1 >> 4)*64 + q0*16 + (r1 & 15)) * 8;
        *(bf16x8*)&sAh[oa0] = ah0; *(bf16x8*)&sAl[oa0] = al0;
        *(bf16x8*)&sAh[oa1] = ah1; *(bf16x8*)&sAl[oa1] = al1;
        *(bf16x8*)&sBh[oa0] = bh0; *(bf16x8*)&sBl[oa0] = bl0;
        *(bf16x8*)&sBh[oa1] = bh1; *(bf16x8*)&sBl[oa1] = bl1;
        __syncthreads();

        bf16x8 fah[4], fal[4], fbh[4], fbl[4];
        #pragma unroll
        for (int t = 0; t < 4; ++t) {
            const int offa = ((wy*4 + t)*64 + lane) * 8;
            const int offb = ((wx*4 + t)*64 + lane) * 8;
            fah[t] = *(const bf16x8*)&sAh[offa];
            fal[t] = *(const bf16x8*)&sAl[offa];
            fbh[t] = *(const bf16x8*)&sBh[offb];
            fbl[t] = *(const bf16x8*)&sBl[offb];
        }
        #pragma unroll
        for (int i = 0; i < 4; ++i)
            #pragma unroll
            for (int j = 0; j < 4; ++j) {
                acc[i][j] = __builtin_amdgcn_mfma_f32_16x16x32_bf16(fah[i], fbh[j], acc[i][j], 0, 0, 0);
                acc[i][j] = __builtin_amdgcn_mfma_f32_16x16x32_bf16(fah[i], fbl[j], acc[i][j], 0, 0, 0);
                acc[i][j] = __builtin_amdgcn_mfma_f32_16x16x32_bf16(fal[i], fbh[j], acc[i][j], 0, 0, 0);
            }
    }

    const int q = lane >> 4, c = lane & 15;
    #pragma unroll
    for (int i = 0; i < 4; ++i)
        #pragma unroll
        for (int j = 0; j < 4; ++j) {
            const int n = n0 + (wx*4 + j)*16 + c;
            const float bv = bias ? bias[n] : 0.f;
            #pragma unroll
            for (int r = 0; r < 4; ++r) {
                const int m = m0 + (wy*4 + i)*16 + q*4 + r;
                Cb[(size_t)m * N + n] = acc[i][j][r] + bv;
            }
        }
}

// ---------------------------------------------------------------------------
// Batched 32x32 transpose: video[b][v][d] -> vT[b][d][v].
// ---------------------------------------------------------------------------
__global__ __launch_bounds__(256) void transpose_kernel(
    const float* __restrict__ in, float* __restrict__ out)
{
    __shared__ float t[32][33];
    const int b = blockIdx.z;
    const int v0 = blockIdx.y * 32, d0 = blockIdx.x * 32;
    const int x = threadIdx.x & 31, y0 = (threadIdx.x >> 5) * 4;
    const float* I = in  + ((size_t)b * V_DIM + v0) * D_DIM + d0;
    #pragma unroll
    for (int r = 0; r < 4; ++r) t[y0 + r][x] = I[(size_t)(y0 + r) * D_DIM + x];
    __syncthreads();
    float* O = out + ((size_t)b * D_DIM + d0) * V_DIM + v0;
    #pragma unroll
    for (int r = 0; r < 4; ++r) O[(size_t)(y0 + r) * V_DIM + x] = t[x][y0 + r];
}

// ---------------------------------------------------------------------------
// Row L2-normalize in place. One wave/row.
// ---------------------------------------------------------------------------
__global__ __launch_bounds__(256) void rownorm_kernel(float* __restrict__ x)
{
    const int wave = threadIdx.x >> 6;
    const int lane = threadIdx.x & 63;
    const size_t r = (size_t)blockIdx.x * 4 + wave;
    float* p = x + r * D_DIM;
    float4 u = *(float4*)(p + lane*4);
    float4 w = *(float4*)(p + 256 + lane*4);
    float ss = u.x*u.x + u.y*u.y + u.z*u.z + u.w*u.w
             + w.x*w.x + w.y*w.y + w.z*w.z + w.w*w.w;
    #pragma unroll
    for (int m = 1; m < 64; m <<= 1) ss += __shfl_xor(ss, m, 64);
    const float inv = 1.0f / fmaxf(sqrtf(ss), 1e-12f);
    u.x*=inv; u.y*=inv; u.z*=inv; u.w*=inv;
    w.x*=inv; w.y*=inv; w.z*=inv; w.w*=inv;
    *(float4*)(p + lane*4)       = u;
    *(float4*)(p + 256 + lane*4) = w;
}

// ---------------------------------------------------------------------------
// Softmax row stats: rmax[r], rinv[r] = 1/sum(exp(s-max)).
// ---------------------------------------------------------------------------
__global__ __launch_bounds__(256) void rowstat_kernel(
    const float* __restrict__ sim, float* __restrict__ rmax, float* __restrict__ rinv)
{
    const int wave = threadIdx.x >> 6;
    const int lane = threadIdx.x & 63;
    const size_t r = (size_t)blockIdx.x * 4 + wave;
    const float* p = sim + r * V_DIM;
    float4 u = *(const float4*)(p + lane*4);
    float4 w = *(const float4*)(p + 256 + lane*4);
    float m = fmaxf(fmaxf(fmaxf(u.x,u.y), fmaxf(u.z,u.w)),
                    fmaxf(fmaxf(w.x,w.y), fmaxf(w.z,w.w)));
    #pragma unroll
    for (int s = 1; s < 64; s <<= 1) m = fmaxf(m, __shfl_xor(m, s, 64));
    float e = __expf(u.x-m)+__expf(u.y-m)+__expf(u.z-m)+__expf(u.w-m)
            + __expf(w.x-m)+__expf(w.y-m)+__expf(w.z-m)+__expf(w.w-m);
    #pragma unroll
    for (int s = 1; s < 64; s <<= 1) e += __shfl_xor(e, s, 64);
    if (lane == 0) { rmax[r] = m; rinv[r] = 1.0f / e; }
}

// ---------------------------------------------------------------------------
// DPP helpers (wave64) — verified R2/R3.
// ---------------------------------------------------------------------------
template <int CTRL, int RMASK>
__device__ __forceinline__ float fdpp(float oldv, float src) {
    int r = __builtin_amdgcn_update_dpp(
        __float_as_int(oldv), __float_as_int(src), CTRL, RMASK, 0xF, false);
    return __int_as_float(r);
}

__device__ __forceinline__ float wave_incl_add(float x) {
    x += fdpp<0x111, 0xF>(0.f, x);
    x += fdpp<0x112, 0xF>(0.f, x);
    x += fdpp<0x114, 0xF>(0.f, x);
    x += fdpp<0x118, 0xF>(0.f, x);
    x += fdpp<0x142, 0xA>(0.f, x);
    x += fdpp<0x143, 0xC>(0.f, x);
    return x;
}

__device__ __forceinline__ float wave_incl_max(float x) {
    x = fmaxf(x, fdpp<0x111, 0xF>(NEGV, x));
    x = fmaxf(x, fdpp<0x112, 0xF>(NEGV, x));
    x = fmaxf(x, fdpp<0x114, 0xF>(NEGV, x));
    x = fmaxf(x, fdpp<0x118, 0xF>(NEGV, x));
    x = fmaxf(x, fdpp<0x142, 0xA>(NEGV, x));
    x = fmaxf(x, fdpp<0x143, 0xC>(NEGV, x));
    return x;
}

// ---------------------------------------------------------------------------
// In-place inclusive prefix sum along each sim row (1 wave per row).
// ---------------------------------------------------------------------------
__global__ __launch_bounds__(256) void rowpsum_kernel(float* __restrict__ sim)
{
    const int wave = threadIdx.x >> 6;
    const int lane = threadIdx.x & 63;
    const size_t r = (size_t)blockIdx.x * 4 + wave;
    float* p = sim + r * V_DIM + lane * 8;
    float4 u = *(float4*)p;
    float4 w = *(float4*)(p + 4);
    float s[8] = {u.x,u.y,u.z,u.w,w.x,w.y,w.z,w.w};
    #pragma unroll
    for (int k = 1; k < 8; ++k) s[k] += s[k-1];
    float excl = fdpp<0x138, 0xF>(0.f, wave_incl_add(s[7]));
    #pragma unroll
    for (int k = 0; k < 8; ++k) s[k] += excl;
    *(float4*)p       = make_float4(s[0], s[1], s[2], s[3]);
    *(float4*)(p + 4) = make_float4(s[4], s[5], s[6], s[7]);
}

// ---------------------------------------------------------------------------
// DTW row step on PRE-SUMMED rows (verified R3).
// ---------------------------------------------------------------------------
__device__ __forceinline__ void dtw_row_p(const float Pk[8], float dp[8], float bnd)
{
    float Pexcl    = fdpp<0x138, 0xF>(0.0f, Pk[7]);
    float prevlast = fdpp<0x138, 0xF>(bnd,  dp[7]);
    float q[8];
    q[0] = fmaxf(dp[0], prevlast) - Pexcl;
    #pragma unroll
    for (int k = 1; k < 8; ++k) q[k] = fmaxf(dp[k], dp[k-1]) - Pk[k-1];
    #pragma unroll
    for (int d = 1; d < 8; d <<= 1)
        #pragma unroll
        for (int k = 7; k >= d; --k) q[k] = fmaxf(q[k], q[k-d]);
    float Qexcl = fdpp<0x138, 0xF>(NEGV, wave_incl_max(q[7]));
    #pragma unroll
    for (int k = 0; k < 8; ++k) dp[k] = Pk[k] + fmaxf(Qexcl, q[k]);
}

// ---------------------------------------------------------------------------
// DTW scan: 1 batch per wave, 16 blocks. Group-double-buffered loads:
// burst-load 8 rows into one register group while computing the other,
// so the vmcnt drain is paid once per 8 rows, not per row.
// ---------------------------------------------------------------------------
__global__ __launch_bounds__(64) void dtw_scan_kernel(
    const float* __restrict__ psum, float* __restrict__ score)
{
    const int b = blockIdx.x;
    const int lane = threadIdx.x;
    const float* S = psum + (size_t)b * A_DIM * V_DIM + lane * 8;

    float dp[8];
    #pragma unroll
    for (int k = 0; k < 8; ++k) dp[k] = NEGV;

    float4 A0[8], B0[8], A1[8], B1[8];
    #pragma unroll
    for (int r = 0; r < 8; ++r) {
        A0[r] = *(const float4*)(S + (size_t)r * V_DIM);
        B0[r] = *(const float4*)(S + (size_t)r * V_DIM + 4);
    }

    const int NG = A_DIM / 8;   // 128 groups (even)
    for (int g = 0; g < NG; g += 2) {
        // prefetch group g+1 while computing group g
        if (g + 1 < NG) {
            #pragma unroll
            for (int r = 0; r < 8; ++r) {
                A1[r] = *(const float4*)(S + (size_t)((g+1)*8 + r) * V_DIM);
                B1[r] = *(const float4*)(S + (size_t)((g+1)*8 + r) * V_DIM + 4);
            }
        }
        #pragma unroll
        for (int r = 0; r < 8; ++r) {
            float P[8] = {A0[r].x,A0[r].y,A0[r].z,A0[r].w,
                          B0[r].x,B0[r].y,B0[r].z,B0[r].w};
            dtw_row_p(P, dp, (g == 0 && r == 0) ? 0.0f : NEGV);
        }
        // prefetch group g+2 while computing group g+1
        if (g + 2 < NG) {
            #pragma unroll
            for (int r = 0; r < 8; ++r) {
                A0[r] = *(const float4*)(S + (size_t)((g+2)*8 + r) * V_DIM);
                B0[r] = *(const float4*)(S + (size_t)((g+2)*8 + r) * V_DIM + 4);
            }
        }
        #pragma unroll
        for (int r = 0; r < 8; ++r) {
            float P[8] = {A1[r].x,A1[r].y,A1[r].z,A1[r].w,
                          B1[r].x,B1[r].y,B1[r].z,B1[r].w};
            dtw_row_p(P, dp, NEGV);
        }
    }
    if (lane == 63) score[b] = dp[7];   // dp[A][V]
}

// ---------------------------------------------------------------------------
extern "C" void kernel_launch(void* const* d_in, const int* in_sizes, int n_in,
                              void* d_out, int out_size, void* d_ws, size_t ws_size,
                              hipStream_t stream)
{
    const float* audio = (const float*)d_in[0];   // [16,1024,512]
    const float* video = (const float*)d_in[1];   // [16, 512,512]
    const float* W     = (const float*)d_in[2];   // [512,512]
    const float* bias  = (const float*)d_in[3];   // [512]

    float* out_aligned = (float*)d_out;                                   // [16,1024,512]
    float* out_score   = (float*)d_out + (size_t)B_DIM * A_DIM * D_DIM;   // [16]

    float* ws   = (float*)d_ws;
    float* a_n  = ws;                                        // 16384 x 512
    float* v_n  = a_n  + (size_t)B_DIM * A_DIM * D_DIM;      //  8192 x 512 (later reused as vT)
    float* sim  = v_n  + (size_t)B_DIM * V_DIM * D_DIM;      // 16 x 1024 x 512
    float* rmax = sim  + (size_t)B_DIM * A_DIM * V_DIM;      // 16384
    float* rinv = rmax + (size_t)B_DIM * A_DIM;              // 16384
    float* vT   = v_n;                                       // [16][512 d][512 v]

    // 1) projections: X @ W^T + b  (split-bf16 MFMA)
    gemm_mfma_kernel<false><<<dim3(D_DIM/128, (B_DIM*A_DIM)/128, 1), dim3(256), 0, stream>>>(
        audio, W, bias, a_n, nullptr, nullptr, B_DIM*A_DIM, D_DIM, D_DIM, 0, 0, 0);
    gemm_mfma_kernel<false><<<dim3(D_DIM/128, (B_DIM*V_DIM)/128, 1), dim3(256), 0, stream>>>(
        video, W, bias, v_n, nullptr, nullptr, B_DIM*V_DIM, D_DIM, D_DIM, 0, 0, 0);

    // 2) L2-normalize all projected rows (a_n, v_n contiguous)
    rownorm_kernel<<<dim3((B_DIM*(A_DIM+V_DIM))/4), dim3(256), 0, stream>>>(a_n);

    // 3) sim[b] = a_n[b] @ v_n[b]^T
    gemm_mfma_kernel<false><<<dim3(V_DIM/128, A_DIM/128, B_DIM), dim3(256), 0, stream>>>(
        a_n, v_n, nullptr, sim, nullptr, nullptr, A_DIM, V_DIM, D_DIM,
        (size_t)A_DIM*D_DIM, (size_t)V_DIM*D_DIM, (size_t)A_DIM*V_DIM);

    // 4) softmax row stats
    rowstat_kernel<<<dim3((B_DIM*A_DIM)/4), dim3(256), 0, stream>>>(sim, rmax, rinv);

    // 5) v_n dead -> transpose video into it for NT PV GEMM
    transpose_kernel<<<dim3(D_DIM/32, V_DIM/32, B_DIM), dim3(256), 0, stream>>>(video, vT);

    // 6) aligned = softmax(sim) @ video  ==  P[A,V] * vT[D,V]^T
    gemm_mfma_kernel<true><<<dim3(D_DIM/128, A_DIM/128, B_DIM), dim3(256), 0, stream>>>(
        sim, vT, nullptr, out_aligned, rmax, rinv, A_DIM, D_DIM, V_DIM,
        (size_t)A_DIM*V_DIM, (size_t)V_DIM*D_DIM, (size_t)A_DIM*D_DIM);

    // 7) in-place row prefix sums of sim (raw sim fully consumed)
    rowpsum_kernel<<<dim3((B_DIM*A_DIM)/4), dim3(256), 0, stream>>>(sim);

    // 8) DTW alignment score (1 batch/wave, 16 blocks, group dbuf)
    dtw_scan_kernel<<<dim3(B_DIM), dim3(64), 0, stream>>>(sim, out_score);
}

// Round 6
// 410.825 us; speedup vs baseline: 2.8126x; 1.1829x over previous
//
#include <hip/hip_runtime.h>
#include <math.h>

#define B_DIM 16
#define A_DIM 1024
#define V_DIM 512
#define D_DIM 512
#define NEGV  (-1e30f)

typedef short bf16x8 __attribute__((ext_vector_type(8)));
typedef float floatx4 __attribute__((ext_vector_type(4)));

// round-to-nearest-even fp32 -> bf16 (bit trick)
__device__ __forceinline__ short bf16_rne(float f) {
    unsigned u = __float_as_uint(f);
    return (short)((u + 0x7fffu + ((u >> 16) & 1u)) >> 16);
}

// ---------------------------------------------------------------------------
// Elementwise fp32 -> bf16 (8 elems/thread).
// ---------------------------------------------------------------------------
__global__ __launch_bounds__(256) void cvt_bf16_kernel(
    const float* __restrict__ in, unsigned short* __restrict__ out, int n8)
{
    const int i = blockIdx.x * 256 + threadIdx.x;
    if (i >= n8) return;
    float4 u = ((const float4*)in)[2*i];
    float4 v = ((const float4*)in)[2*i + 1];
    bf16x8 h;
    h[0]=bf16_rne(u.x); h[1]=bf16_rne(u.y); h[2]=bf16_rne(u.z); h[3]=bf16_rne(u.w);
    h[4]=bf16_rne(v.x); h[5]=bf16_rne(v.y); h[6]=bf16_rne(v.z); h[7]=bf16_rne(v.w);
    *(bf16x8*)(out + (size_t)i * 8) = h;
}

// ---------------------------------------------------------------------------
// Plain-bf16 MFMA NT GEMM: C[M,N] = A[M,K]*B[N,K]^T (+bias), batched strides.
// 128x128 tile, BK=32, 256 threads (4 waves, 2x2 grid of 64x64 wave tiles).
// LDS in MFMA fragment order; staging = 4x16B loads + 4x ds_write_b128/thread.
// ---------------------------------------------------------------------------
__global__ __launch_bounds__(256) void gemm_bf16_nt(
    const unsigned short* __restrict__ Ag, const unsigned short* __restrict__ Bg,
    const float* __restrict__ bias, float* __restrict__ Cg,
    int M, int N, int K, size_t strA, size_t strB, size_t strC)
{
    __shared__ __align__(16) unsigned short lA[8*64*8];   // 8 KB
    __shared__ __align__(16) unsigned short lB[8*64*8];

    const unsigned short* Ab = Ag + (size_t)blockIdx.z * strA;
    const unsigned short* Bb = Bg + (size_t)blockIdx.z * strB;
    float*                Cb = Cg + (size_t)blockIdx.z * strC;

    const int m0 = blockIdx.y * 128;
    const int n0 = blockIdx.x * 128;
    const int tid = threadIdx.x, lane = tid & 63;
    const int w = tid >> 6, wy = w >> 1, wx = w & 1;

    // staging unit u (0..511): tile=u>>6, m=u&15, q=(u>>4)&3; lane order = unit
    // order within tile -> conflict-free ds_write_b128 and correct frag layout.
    const int u0 = tid, u1 = tid + 256;
    const int r_u0 = ((u0 >> 6) << 4) + (u0 & 15), k_u0 = ((u0 >> 4) & 3) * 8;
    const int r_u1 = ((u1 >> 6) << 4) + (u1 & 15), k_u1 = ((u1 >> 4) & 3) * 8;

    const unsigned short* gA0 = Ab + (size_t)(m0 + r_u0) * K + k_u0;
    const unsigned short* gA1 = Ab + (size_t)(m0 + r_u1) * K + k_u1;
    const unsigned short* gB0 = Bb + (size_t)(n0 + r_u0) * K + k_u0;
    const unsigned short* gB1 = Bb + (size_t)(n0 + r_u1) * K + k_u1;

    floatx4 acc[4][4];
    #pragma unroll
    for (int i = 0; i < 4; ++i)
        #pragma unroll
        for (int j = 0; j < 4; ++j) acc[i][j] = (floatx4){0.f, 0.f, 0.f, 0.f};

    for (int k0 = 0; k0 < K; k0 += 32) {
        bf16x8 a0 = *(const bf16x8*)(gA0 + k0);
        bf16x8 a1 = *(const bf16x8*)(gA1 + k0);
        bf16x8 b0 = *(const bf16x8*)(gB0 + k0);
        bf16x8 b1 = *(const bf16x8*)(gB1 + k0);
        __syncthreads();
        *(bf16x8*)&lA[(size_t)u0 * 8] = a0;
        *(bf16x8*)&lA[(size_t)u1 * 8] = a1;
        *(bf16x8*)&lB[(size_t)u0 * 8] = b0;
        *(bf16x8*)&lB[(size_t)u1 * 8] = b1;
        __syncthreads();

        bf16x8 fa[4], fb[4];
        #pragma unroll
        for (int t = 0; t < 4; ++t) {
            fa[t] = *(const bf16x8*)&lA[(((wy*4 + t)*64) + lane) * 8];
            fb[t] = *(const bf16x8*)&lB[(((wx*4 + t)*64) + lane) * 8];
        }
        #pragma unroll
        for (int i = 0; i < 4; ++i)
            #pragma unroll
            for (int j = 0; j < 4; ++j)
                acc[i][j] = __builtin_amdgcn_mfma_f32_16x16x32_bf16(fa[i], fb[j], acc[i][j], 0, 0, 0);
    }

    // epilogue: D row = quad*4 + reg, col = lane&15 (verified R4)
    const int q = lane >> 4, c = lane & 15;
    #pragma unroll
    for (int i = 0; i < 4; ++i)
        #pragma unroll
        for (int j = 0; j < 4; ++j) {
            const int n = n0 + (wx*4 + j)*16 + c;
            const float bv = bias ? bias[n] : 0.f;
            #pragma unroll
            for (int r = 0; r < 4; ++r) {
                const int m = m0 + (wy*4 + i)*16 + q*4 + r;
                Cb[(size_t)m * N + n] = acc[i][j][r] + bv;
            }
        }
}

// ---------------------------------------------------------------------------
// Row L2-normalize fp32 -> bf16. One wave/row (512 cols).
// ---------------------------------------------------------------------------
__global__ __launch_bounds__(256) void rownorm_cvt_kernel(
    const float* __restrict__ in, unsigned short* __restrict__ out)
{
    const int wave = threadIdx.x >> 6;
    const int lane = threadIdx.x & 63;
    const size_t r = (size_t)blockIdx.x * 4 + wave;
    const float* p = in + r * D_DIM + lane * 8;
    float4 u = *(const float4*)p;
    float4 w = *(const float4*)(p + 4);
    float ss = u.x*u.x + u.y*u.y + u.z*u.z + u.w*u.w
             + w.x*w.x + w.y*w.y + w.z*w.z + w.w*w.w;
    #pragma unroll
    for (int m = 1; m < 64; m <<= 1) ss += __shfl_xor(ss, m, 64);
    const float inv = 1.0f / fmaxf(sqrtf(ss), 1e-12f);
    bf16x8 h;
    h[0]=bf16_rne(u.x*inv); h[1]=bf16_rne(u.y*inv); h[2]=bf16_rne(u.z*inv); h[3]=bf16_rne(u.w*inv);
    h[4]=bf16_rne(w.x*inv); h[5]=bf16_rne(w.y*inv); h[6]=bf16_rne(w.z*inv); h[7]=bf16_rne(w.w*inv);
    *(bf16x8*)(out + r * D_DIM + lane * 8) = h;
}

// ---------------------------------------------------------------------------
// Softmax row stats: rmax[r], rinv[r] = 1/sum(exp(s-max)).
// ---------------------------------------------------------------------------
__global__ __launch_bounds__(256) void rowstat_kernel(
    const float* __restrict__ sim, float* __restrict__ rmax, float* __restrict__ rinv)
{
    const int wave = threadIdx.x >> 6;
    const int lane = threadIdx.x & 63;
    const size_t r = (size_t)blockIdx.x * 4 + wave;
    const float* p = sim + r * V_DIM;
    float4 u = *(const float4*)(p + lane*4);
    float4 w = *(const float4*)(p + 256 + lane*4);
    float m = fmaxf(fmaxf(fmaxf(u.x,u.y), fmaxf(u.z,u.w)),
                    fmaxf(fmaxf(w.x,w.y), fmaxf(w.z,w.w)));
    #pragma unroll
    for (int s = 1; s < 64; s <<= 1) m = fmaxf(m, __shfl_xor(m, s, 64));
    float e = __expf(u.x-m)+__expf(u.y-m)+__expf(u.z-m)+__expf(u.w-m)
            + __expf(w.x-m)+__expf(w.y-m)+__expf(w.z-m)+__expf(w.w-m);
    #pragma unroll
    for (int s = 1; s < 64; s <<= 1) e += __shfl_xor(e, s, 64);
    if (lane == 0) { rmax[r] = m; rinv[r] = 1.0f / e; }
}

// ---------------------------------------------------------------------------
// DPP helpers (wave64) — verified R2/R3.
// ---------------------------------------------------------------------------
template <int CTRL, int RMASK>
__device__ __forceinline__ float fdpp(float oldv, float src) {
    int r = __builtin_amdgcn_update_dpp(
        __float_as_int(oldv), __float_as_int(src), CTRL, RMASK, 0xF, false);
    return __int_as_float(r);
}

__device__ __forceinline__ float wave_incl_add(float x) {
    x += fdpp<0x111, 0xF>(0.f, x);
    x += fdpp<0x112, 0xF>(0.f, x);
    x += fdpp<0x114, 0xF>(0.f, x);
    x += fdpp<0x118, 0xF>(0.f, x);
    x += fdpp<0x142, 0xA>(0.f, x);
    x += fdpp<0x143, 0xC>(0.f, x);
    return x;
}

__device__ __forceinline__ float wave_incl_max(float x) {
    x = fmaxf(x, fdpp<0x111, 0xF>(NEGV, x));
    x = fmaxf(x, fdpp<0x112, 0xF>(NEGV, x));
    x = fmaxf(x, fdpp<0x114, 0xF>(NEGV, x));
    x = fmaxf(x, fdpp<0x118, 0xF>(NEGV, x));
    x = fmaxf(x, fdpp<0x142, 0xA>(NEGV, x));
    x = fmaxf(x, fdpp<0x143, 0xC>(NEGV, x));
    return x;
}

// ---------------------------------------------------------------------------
// Fused: P = softmax(sim) -> bf16 (for PV GEMM)  AND  sim := row prefix-sum
// in place (for DTW). One wave/row.
// ---------------------------------------------------------------------------
__global__ __launch_bounds__(256) void softmax_psum_kernel(
    float* __restrict__ sim, const float* __restrict__ rmax,
    const float* __restrict__ rinv, unsigned short* __restrict__ Pbf)
{
    const int wave = threadIdx.x >> 6;
    const int lane = threadIdx.x & 63;
    const size_t r = (size_t)blockIdx.x * 4 + wave;
    float* p = sim + r * V_DIM + lane * 8;
    float4 u = *(float4*)p;
    float4 w = *(float4*)(p + 4);
    float s[8] = {u.x,u.y,u.z,u.w,w.x,w.y,w.z,w.w};

    const float rm = rmax[r], ri = rinv[r];
    const float L2E = 1.44269504f;
    bf16x8 h;
    #pragma unroll
    for (int k = 0; k < 8; ++k) h[k] = bf16_rne(exp2f((s[k] - rm) * L2E) * ri);
    *(bf16x8*)(Pbf + r * V_DIM + lane * 8) = h;

    #pragma unroll
    for (int k = 1; k < 8; ++k) s[k] += s[k-1];
    float excl = fdpp<0x138, 0xF>(0.f, wave_incl_add(s[7]));
    #pragma unroll
    for (int k = 0; k < 8; ++k) s[k] += excl;
    *(float4*)p       = make_float4(s[0], s[1], s[2], s[3]);
    *(float4*)(p + 4) = make_float4(s[4], s[5], s[6], s[7]);
}

// ---------------------------------------------------------------------------
// Batched 32x32 transpose + cvt: video[b][v][d] fp32 -> vT[b][d][v] bf16.
// ---------------------------------------------------------------------------
__global__ __launch_bounds__(256) void transpose_cvt_kernel(
    const float* __restrict__ in, unsigned short* __restrict__ out)
{
    __shared__ float t[32][33];
    const int b = blockIdx.z;
    const int v0 = blockIdx.y * 32, d0 = blockIdx.x * 32;
    const int x = threadIdx.x & 31, y0 = (threadIdx.x >> 5) * 4;
    const float* I = in + ((size_t)b * V_DIM + v0) * D_DIM + d0;
    #pragma unroll
    for (int r = 0; r < 4; ++r) t[y0 + r][x] = I[(size_t)(y0 + r) * D_DIM + x];
    __syncthreads();
    unsigned short* O = out + ((size_t)b * D_DIM + d0) * V_DIM + v0;
    #pragma unroll
    for (int r = 0; r < 4; ++r) O[(size_t)(y0 + r) * V_DIM + x] = (unsigned short)bf16_rne(t[x][y0 + r]);
}

// ---------------------------------------------------------------------------
// DTW row step on PRE-SUMMED rows (verified R3).
// ---------------------------------------------------------------------------
__device__ __forceinline__ void dtw_row_p(const float Pk[8], float dp[8], float bnd)
{
    float Pexcl    = fdpp<0x138, 0xF>(0.0f, Pk[7]);
    float prevlast = fdpp<0x138, 0xF>(bnd,  dp[7]);
    float q[8];
    q[0] = fmaxf(dp[0], prevlast) - Pexcl;
    #pragma unroll
    for (int k = 1; k < 8; ++k) q[k] = fmaxf(dp[k], dp[k-1]) - Pk[k-1];
    #pragma unroll
    for (int d = 1; d < 8; d <<= 1)
        #pragma unroll
        for (int k = 7; k >= d; --k) q[k] = fmaxf(q[k], q[k-d]);
    float Qexcl = fdpp<0x138, 0xF>(NEGV, wave_incl_max(q[7]));
    #pragma unroll
    for (int k = 0; k < 8; ++k) dp[k] = Pk[k] + fmaxf(Qexcl, q[k]);
}

// ---------------------------------------------------------------------------
// DTW scan: 1 batch per wave, 16 blocks, group-double-buffered loads
// (verified R5: vmcnt drain amortized over 8 rows).
// ---------------------------------------------------------------------------
__global__ __launch_bounds__(64) void dtw_scan_kernel(
    const float* __restrict__ psum, float* __restrict__ score)
{
    const int b = blockIdx.x;
    const int lane = threadIdx.x;
    const float* S = psum + (size_t)b * A_DIM * V_DIM + lane * 8;

    float dp[8];
    #pragma unroll
    for (int k = 0; k < 8; ++k) dp[k] = NEGV;

    float4 A0[8], B0[8], A1[8], B1[8];
    #pragma unroll
    for (int r = 0; r < 8; ++r) {
        A0[r] = *(const float4*)(S + (size_t)r * V_DIM);
        B0[r] = *(const float4*)(S + (size_t)r * V_DIM + 4);
    }

    const int NG = A_DIM / 8;
    for (int g = 0; g < NG; g += 2) {
        if (g + 1 < NG) {
            #pragma unroll
            for (int r = 0; r < 8; ++r) {
                A1[r] = *(const float4*)(S + (size_t)((g+1)*8 + r) * V_DIM);
                B1[r] = *(const float4*)(S + (size_t)((g+1)*8 + r) * V_DIM + 4);
            }
        }
        #pragma unroll
        for (int r = 0; r < 8; ++r) {
            float P[8] = {A0[r].x,A0[r].y,A0[r].z,A0[r].w,
                          B0[r].x,B0[r].y,B0[r].z,B0[r].w};
            dtw_row_p(P, dp, (g == 0 && r == 0) ? 0.0f : NEGV);
        }
        if (g + 2 < NG) {
            #pragma unroll
            for (int r = 0; r < 8; ++r) {
                A0[r] = *(const float4*)(S + (size_t)((g+2)*8 + r) * V_DIM);
                B0[r] = *(const float4*)(S + (size_t)((g+2)*8 + r) * V_DIM + 4);
            }
        }
        #pragma unroll
        for (int r = 0; r < 8; ++r) {
            float P[8] = {A1[r].x,A1[r].y,A1[r].z,A1[r].w,
                          B1[r].x,B1[r].y,B1[r].z,B1[r].w};
            dtw_row_p(P, dp, NEGV);
        }
    }
    if (lane == 63) score[b] = dp[7];
}

// ---------------------------------------------------------------------------
extern "C" void kernel_launch(void* const* d_in, const int* in_sizes, int n_in,
                              void* d_out, int out_size, void* d_ws, size_t ws_size,
                              hipStream_t stream)
{
    const float* audio = (const float*)d_in[0];   // [16,1024,512]
    const float* video = (const float*)d_in[1];   // [16, 512,512]
    const float* W     = (const float*)d_in[2];   // [512,512]
    const float* bias  = (const float*)d_in[3];   // [512]

    float* out_aligned = (float*)d_out;
    float* out_score   = (float*)d_out + (size_t)B_DIM * A_DIM * D_DIM;

    const size_t NA = (size_t)B_DIM * A_DIM * D_DIM;   // 8.39M
    const size_t NV = (size_t)B_DIM * V_DIM * D_DIM;   // 4.19M
    const size_t NS = (size_t)B_DIM * A_DIM * V_DIM;   // 8.39M

    float* ws = (float*)d_ws;
    float*          a_p  = ws;                         // NA fp32          [dead after rownorm_a]
    float*          v_p  = a_p + NA;                   // NV fp32          [dead after rownorm_v]
    float*          sim  = v_p + NV;                   // NS fp32
    unsigned short* abf  = (unsigned short*)(sim + NS);        // NA bf16  [dead after proj-a]
    unsigned short* vbf  = (unsigned short*)(sim + NS) + NA;   // NV bf16  [dead after proj-v]
    unsigned short* v_nb = vbf + NV;                   // NV bf16
    unsigned short* Wbf  = v_nb + NV;                  // 262144 bf16
    float*          rmax = (float*)(Wbf + D_DIM*D_DIM);
    float*          rinv = rmax + B_DIM * A_DIM;
    unsigned short* a_nb = (unsigned short*)v_p;       // NA bf16, reuses dead v_p+half of a_p?  NO:
    // a_nb (NA bf16 = NA/2 floats) fits entirely in v_p's NV floats since NA/2 == NV. OK.
    unsigned short* Pbf  = abf;                        // NS bf16 == NA bf16, reuses dead abf
    unsigned short* vTb  = vbf;                        // NV bf16, reuses dead vbf

    // 1) fp32 -> bf16 input conversions
    cvt_bf16_kernel<<<dim3((int)(NA/8/256)), dim3(256), 0, stream>>>(audio, abf, (int)(NA/8));
    cvt_bf16_kernel<<<dim3((int)(NV/8/256)), dim3(256), 0, stream>>>(video, vbf, (int)(NV/8));
    cvt_bf16_kernel<<<dim3(D_DIM*D_DIM/8/256), dim3(256), 0, stream>>>(W, Wbf, D_DIM*D_DIM/8);

    // 2) projections: X @ W^T + b   (bf16 MFMA, fp32 out)
    gemm_bf16_nt<<<dim3(D_DIM/128, (B_DIM*A_DIM)/128, 1), dim3(256), 0, stream>>>(
        abf, Wbf, bias, a_p, B_DIM*A_DIM, D_DIM, D_DIM, 0, 0, 0);
    gemm_bf16_nt<<<dim3(D_DIM/128, (B_DIM*V_DIM)/128, 1), dim3(256), 0, stream>>>(
        vbf, Wbf, bias, v_p, B_DIM*V_DIM, D_DIM, D_DIM, 0, 0, 0);

    // 3) normalize -> bf16.  v first (frees v_p), then a into v_p's space.
    rownorm_cvt_kernel<<<dim3((B_DIM*V_DIM)/4), dim3(256), 0, stream>>>(v_p, v_nb);
    rownorm_cvt_kernel<<<dim3((B_DIM*A_DIM)/4), dim3(256), 0, stream>>>(a_p, a_nb);

    // 4) sim[b] = a_n[b] @ v_n[b]^T  (bf16 MFMA, fp32 out)
    gemm_bf16_nt<<<dim3(V_DIM/128, A_DIM/128, B_DIM), dim3(256), 0, stream>>>(
        a_nb, v_nb, nullptr, sim, A_DIM, V_DIM, D_DIM,
        (size_t)A_DIM*D_DIM, (size_t)V_DIM*D_DIM, (size_t)A_DIM*V_DIM);

    // 5) softmax row stats
    rowstat_kernel<<<dim3((B_DIM*A_DIM)/4), dim3(256), 0, stream>>>(sim, rmax, rinv);

    // 6) fused softmax->bf16 (Pbf) + in-place row prefix sum (sim)
    softmax_psum_kernel<<<dim3((B_DIM*A_DIM)/4), dim3(256), 0, stream>>>(sim, rmax, rinv, Pbf);

    // 7) video -> vT bf16 (for NT PV GEMM)
    transpose_cvt_kernel<<<dim3(D_DIM/32, V_DIM/32, B_DIM), dim3(256), 0, stream>>>(video, vTb);

    // 8) aligned = P @ video == Pbf[A,V] * vTb[D,V]^T
    gemm_bf16_nt<<<dim3(D_DIM/128, A_DIM/128, B_DIM), dim3(256), 0, stream>>>(
        Pbf, vTb, nullptr, out_aligned, A_DIM, D_DIM, V_DIM,
        (size_t)A_DIM*V_DIM, (size_t)V_DIM*D_DIM, (size_t)A_DIM*D_DIM);

    // 9) DTW alignment score
    dtw_scan_kernel<<<dim3(B_DIM), dim3(64), 0, stream>>>(sim, out_score);
}

// Round 7
// 379.875 us; speedup vs baseline: 3.0417x; 1.0815x over previous
//
#include <hip/hip_runtime.h>
#include <math.h>

#define B_DIM 16
#define A_DIM 1024
#define V_DIM 512
#define D_DIM 512
#define NEGV  (-1e30f)

typedef short bf16x8 __attribute__((ext_vector_type(8)));
typedef float floatx4 __attribute__((ext_vector_type(4)));

// round-to-nearest-even fp32 -> bf16
__device__ __forceinline__ short bf16_rne(float f) {
    unsigned u = __float_as_uint(f);
    return (short)((u + 0x7fffu + ((u >> 16) & 1u)) >> 16);
}

// ---------------------------------------------------------------------------
// Elementwise fp32 -> bf16 (8 elems/thread).
// ---------------------------------------------------------------------------
__global__ __launch_bounds__(256) void cvt_bf16_kernel(
    const float* __restrict__ in, unsigned short* __restrict__ out, int n8)
{
    const int i = blockIdx.x * 256 + threadIdx.x;
    if (i >= n8) return;
    float4 u = ((const float4*)in)[2*i];
    float4 v = ((const float4*)in)[2*i + 1];
    bf16x8 h;
    h[0]=bf16_rne(u.x); h[1]=bf16_rne(u.y); h[2]=bf16_rne(u.z); h[3]=bf16_rne(u.w);
    h[4]=bf16_rne(v.x); h[5]=bf16_rne(v.y); h[6]=bf16_rne(v.z); h[7]=bf16_rne(v.w);
    *(bf16x8*)(out + (size_t)i * 8) = h;
}

// ---------------------------------------------------------------------------
// bf16 MFMA NT GEMM with register-prefetch K-pipeline.
// 128x128 tile, BK=32, 256 threads (4 waves, 2x2 grid of 64x64 wave tiles).
// Next K-slice's global loads are issued right after barrier-2, so HBM/L2
// latency overlaps the 8 ds_read_b128 + 16 MFMAs instead of the ds_write.
// ---------------------------------------------------------------------------
__global__ __launch_bounds__(256) void gemm_bf16_nt(
    const unsigned short* __restrict__ Ag, const unsigned short* __restrict__ Bg,
    const float* __restrict__ bias, float* __restrict__ Cg,
    int M, int N, int K, size_t strA, size_t strB, size_t strC)
{
    __shared__ __align__(16) unsigned short lA[8*64*8];   // 8 KB
    __shared__ __align__(16) unsigned short lB[8*64*8];

    const unsigned short* Ab = Ag + (size_t)blockIdx.z * strA;
    const unsigned short* Bb = Bg + (size_t)blockIdx.z * strB;
    float*                Cb = Cg + (size_t)blockIdx.z * strC;

    const int m0 = blockIdx.y * 128;
    const int n0 = blockIdx.x * 128;
    const int tid = threadIdx.x, lane = tid & 63;
    const int w = tid >> 6, wy = w >> 1, wx = w & 1;

    const int u0 = tid, u1 = tid + 256;
    const int r_u0 = ((u0 >> 6) << 4) + (u0 & 15), k_u0 = ((u0 >> 4) & 3) * 8;
    const int r_u1 = ((u1 >> 6) << 4) + (u1 & 15), k_u1 = ((u1 >> 4) & 3) * 8;

    const unsigned short* gA0 = Ab + (size_t)(m0 + r_u0) * K + k_u0;
    const unsigned short* gA1 = Ab + (size_t)(m0 + r_u1) * K + k_u1;
    const unsigned short* gB0 = Bb + (size_t)(n0 + r_u0) * K + k_u0;
    const unsigned short* gB1 = Bb + (size_t)(n0 + r_u1) * K + k_u1;

    floatx4 acc[4][4];
    #pragma unroll
    for (int i = 0; i < 4; ++i)
        #pragma unroll
        for (int j = 0; j < 4; ++j) acc[i][j] = (floatx4){0.f, 0.f, 0.f, 0.f};

    // preload K-slice 0
    bf16x8 a0 = *(const bf16x8*)(gA0);
    bf16x8 a1 = *(const bf16x8*)(gA1);
    bf16x8 b0 = *(const bf16x8*)(gB0);
    bf16x8 b1 = *(const bf16x8*)(gB1);

    for (int k0 = 0; k0 < K; k0 += 32) {
        __syncthreads();
        *(bf16x8*)&lA[(size_t)u0 * 8] = a0;
        *(bf16x8*)&lA[(size_t)u1 * 8] = a1;
        *(bf16x8*)&lB[(size_t)u0 * 8] = b0;
        *(bf16x8*)&lB[(size_t)u1 * 8] = b1;
        __syncthreads();

        if (k0 + 32 < K) {                    // issue next slice early
            a0 = *(const bf16x8*)(gA0 + k0 + 32);
            a1 = *(const bf16x8*)(gA1 + k0 + 32);
            b0 = *(const bf16x8*)(gB0 + k0 + 32);
            b1 = *(const bf16x8*)(gB1 + k0 + 32);
        }

        bf16x8 fa[4], fb[4];
        #pragma unroll
        for (int t = 0; t < 4; ++t) {
            fa[t] = *(const bf16x8*)&lA[(((wy*4 + t)*64) + lane) * 8];
            fb[t] = *(const bf16x8*)&lB[(((wx*4 + t)*64) + lane) * 8];
        }
        #pragma unroll
        for (int i = 0; i < 4; ++i)
            #pragma unroll
            for (int j = 0; j < 4; ++j)
                acc[i][j] = __builtin_amdgcn_mfma_f32_16x16x32_bf16(fa[i], fb[j], acc[i][j], 0, 0, 0);
    }

    const int q = lane >> 4, c = lane & 15;
    #pragma unroll
    for (int i = 0; i < 4; ++i)
        #pragma unroll
        for (int j = 0; j < 4; ++j) {
            const int n = n0 + (wx*4 + j)*16 + c;
            const float bv = bias ? bias[n] : 0.f;
            #pragma unroll
            for (int r = 0; r < 4; ++r) {
                const int m = m0 + (wy*4 + i)*16 + q*4 + r;
                Cb[(size_t)m * N + n] = acc[i][j][r] + bv;
            }
        }
}

// ---------------------------------------------------------------------------
// Row L2-normalize fp32 -> bf16. One wave/row (512 cols).
// ---------------------------------------------------------------------------
__global__ __launch_bounds__(256) void rownorm_cvt_kernel(
    const float* __restrict__ in, unsigned short* __restrict__ out)
{
    const int wave = threadIdx.x >> 6;
    const int lane = threadIdx.x & 63;
    const size_t r = (size_t)blockIdx.x * 4 + wave;
    const float* p = in + r * D_DIM + lane * 8;
    float4 u = *(const float4*)p;
    float4 w = *(const float4*)(p + 4);
    float ss = u.x*u.x + u.y*u.y + u.z*u.z + u.w*u.w
             + w.x*w.x + w.y*w.y + w.z*w.z + w.w*w.w;
    #pragma unroll
    for (int m = 1; m < 64; m <<= 1) ss += __shfl_xor(ss, m, 64);
    const float inv = 1.0f / fmaxf(sqrtf(ss), 1e-12f);
    bf16x8 h;
    h[0]=bf16_rne(u.x*inv); h[1]=bf16_rne(u.y*inv); h[2]=bf16_rne(u.z*inv); h[3]=bf16_rne(u.w*inv);
    h[4]=bf16_rne(w.x*inv); h[5]=bf16_rne(w.y*inv); h[6]=bf16_rne(w.z*inv); h[7]=bf16_rne(w.w*inv);
    *(bf16x8*)(out + r * D_DIM + lane * 8) = h;
}

// ---------------------------------------------------------------------------
// DPP helpers (wave64) — verified R2/R3.
// ---------------------------------------------------------------------------
template <int CTRL, int RMASK>
__device__ __forceinline__ float fdpp(float oldv, float src) {
    int r = __builtin_amdgcn_update_dpp(
        __float_as_int(oldv), __float_as_int(src), CTRL, RMASK, 0xF, false);
    return __int_as_float(r);
}

__device__ __forceinline__ float wave_incl_add(float x) {
    x += fdpp<0x111, 0xF>(0.f, x);
    x += fdpp<0x112, 0xF>(0.f, x);
    x += fdpp<0x114, 0xF>(0.f, x);
    x += fdpp<0x118, 0xF>(0.f, x);
    x += fdpp<0x142, 0xA>(0.f, x);
    x += fdpp<0x143, 0xC>(0.f, x);
    return x;
}

__device__ __forceinline__ float wave_incl_max(float x) {
    x = fmaxf(x, fdpp<0x111, 0xF>(NEGV, x));
    x = fmaxf(x, fdpp<0x112, 0xF>(NEGV, x));
    x = fmaxf(x, fdpp<0x114, 0xF>(NEGV, x));
    x = fmaxf(x, fdpp<0x118, 0xF>(NEGV, x));
    x = fmaxf(x, fdpp<0x142, 0xA>(NEGV, x));
    x = fmaxf(x, fdpp<0x143, 0xC>(NEGV, x));
    return x;
}

// ---------------------------------------------------------------------------
// Fused: row max + denom + P=softmax->bf16 + in-place row prefix sum.
// One wave/row, row resident in 8 regs/lane. Replaces rowstat+softmax_psum.
// ---------------------------------------------------------------------------
__global__ __launch_bounds__(256) void softmax_psum_fused(
    float* __restrict__ sim, unsigned short* __restrict__ Pbf)
{
    const int wave = threadIdx.x >> 6;
    const int lane = threadIdx.x & 63;
    const size_t r = (size_t)blockIdx.x * 4 + wave;
    float* p = sim + r * V_DIM + lane * 8;
    float4 u = *(float4*)p;
    float4 w = *(float4*)(p + 4);
    float s[8] = {u.x,u.y,u.z,u.w,w.x,w.y,w.z,w.w};

    float m = s[0];
    #pragma unroll
    for (int k = 1; k < 8; ++k) m = fmaxf(m, s[k]);
    #pragma unroll
    for (int t = 1; t < 64; t <<= 1) m = fmaxf(m, __shfl_xor(m, t, 64));

    const float L2E = 1.44269504f;
    float ex[8];
    float e = 0.f;
    #pragma unroll
    for (int k = 0; k < 8; ++k) { ex[k] = exp2f((s[k] - m) * L2E); e += ex[k]; }
    #pragma unroll
    for (int t = 1; t < 64; t <<= 1) e += __shfl_xor(e, t, 64);
    const float ri = 1.0f / e;

    bf16x8 h;
    #pragma unroll
    for (int k = 0; k < 8; ++k) h[k] = bf16_rne(ex[k] * ri);
    *(bf16x8*)(Pbf + r * V_DIM + lane * 8) = h;

    #pragma unroll
    for (int k = 1; k < 8; ++k) s[k] += s[k-1];
    float excl = fdpp<0x138, 0xF>(0.f, wave_incl_add(s[7]));
    #pragma unroll
    for (int k = 0; k < 8; ++k) s[k] += excl;
    *(float4*)p       = make_float4(s[0], s[1], s[2], s[3]);
    *(float4*)(p + 4) = make_float4(s[4], s[5], s[6], s[7]);
}

// ---------------------------------------------------------------------------
// Batched 32x32 transpose + cvt: video[b][v][d] fp32 -> vT[b][d][v] bf16.
// ---------------------------------------------------------------------------
__global__ __launch_bounds__(256) void transpose_cvt_kernel(
    const float* __restrict__ in, unsigned short* __restrict__ out)
{
    __shared__ float t[32][33];
    const int b = blockIdx.z;
    const int v0 = blockIdx.y * 32, d0 = blockIdx.x * 32;
    const int x = threadIdx.x & 31, y0 = (threadIdx.x >> 5) * 4;
    const float* I = in + ((size_t)b * V_DIM + v0) * D_DIM + d0;
    #pragma unroll
    for (int r = 0; r < 4; ++r) t[y0 + r][x] = I[(size_t)(y0 + r) * D_DIM + x];
    __syncthreads();
    unsigned short* O = out + ((size_t)b * D_DIM + d0) * V_DIM + v0;
    #pragma unroll
    for (int r = 0; r < 4; ++r) O[(size_t)(y0 + r) * V_DIM + x] = (unsigned short)bf16_rne(t[x][y0 + r]);
}

// ---------------------------------------------------------------------------
// DTW row step on PRE-SUMMED rows (verified R3).
// ---------------------------------------------------------------------------
__device__ __forceinline__ void dtw_row_p(const float Pk[8], float dp[8], float bnd)
{
    float Pexcl    = fdpp<0x138, 0xF>(0.0f, Pk[7]);
    float prevlast = fdpp<0x138, 0xF>(bnd,  dp[7]);
    float q[8];
    q[0] = fmaxf(dp[0], prevlast) - Pexcl;
    #pragma unroll
    for (int k = 1; k < 8; ++k) q[k] = fmaxf(dp[k], dp[k-1]) - Pk[k-1];
    #pragma unroll
    for (int d = 1; d < 8; d <<= 1)
        #pragma unroll
        for (int k = 7; k >= d; --k) q[k] = fmaxf(q[k], q[k-d]);
    float Qexcl = fdpp<0x138, 0xF>(NEGV, wave_incl_max(q[7]));
    #pragma unroll
    for (int k = 0; k < 8; ++k) dp[k] = Pk[k] + fmaxf(Qexcl, q[k]);
}

// ---------------------------------------------------------------------------
// Fused PV GEMM + DTW, one dispatch so DTW's 16 latency-bound blocks hide the
// whole PV GEMM. Blocks 0..15: DTW (R5-verified body, 64 active threads).
// Blocks 16..527: PV = Pbf[A,V] * vTb[D,V]^T -> out_aligned (reg-prefetch
// pipeline as gemm_bf16_nt). All 528 blocks co-resident at ~3 blocks/CU.
// ---------------------------------------------------------------------------
__global__ __launch_bounds__(256) void pv_dtw_kernel(
    const unsigned short* __restrict__ Pbf, const unsigned short* __restrict__ vTb,
    const float* __restrict__ psum, float* __restrict__ out_aligned,
    float* __restrict__ out_score)
{
    __shared__ __align__(16) unsigned short lA[8*64*8];
    __shared__ __align__(16) unsigned short lB[8*64*8];

    if (blockIdx.x < 16) {
        // ---------------- DTW path ----------------
        if (threadIdx.x >= 64) return;
        const int b = blockIdx.x;
        const int lane = threadIdx.x;
        const float* S = psum + (size_t)b * A_DIM * V_DIM + lane * 8;

        float dp[8];
        #pragma unroll
        for (int k = 0; k < 8; ++k) dp[k] = NEGV;

        float4 A0[8], B0[8], A1[8], B1[8];
        #pragma unroll
        for (int r = 0; r < 8; ++r) {
            A0[r] = *(const float4*)(S + (size_t)r * V_DIM);
            B0[r] = *(const float4*)(S + (size_t)r * V_DIM + 4);
        }
        const int NG = A_DIM / 8;
        for (int g = 0; g < NG; g += 2) {
            if (g + 1 < NG) {
                #pragma unroll
                for (int r = 0; r < 8; ++r) {
                    A1[r] = *(const float4*)(S + (size_t)((g+1)*8 + r) * V_DIM);
                    B1[r] = *(const float4*)(S + (size_t)((g+1)*8 + r) * V_DIM + 4);
                }
            }
            #pragma unroll
            for (int r = 0; r < 8; ++r) {
                float P[8] = {A0[r].x,A0[r].y,A0[r].z,A0[r].w,
                              B0[r].x,B0[r].y,B0[r].z,B0[r].w};
                dtw_row_p(P, dp, (g == 0 && r == 0) ? 0.0f : NEGV);
            }
            if (g + 2 < NG) {
                #pragma unroll
                for (int r = 0; r < 8; ++r) {
                    A0[r] = *(const float4*)(S + (size_t)((g+2)*8 + r) * V_DIM);
                    B0[r] = *(const float4*)(S + (size_t)((g+2)*8 + r) * V_DIM + 4);
                }
            }
            #pragma unroll
            for (int r = 0; r < 8; ++r) {
                float P[8] = {A1[r].x,A1[r].y,A1[r].z,A1[r].w,
                              B1[r].x,B1[r].y,B1[r].z,B1[r].w};
                dtw_row_p(P, dp, NEGV);
            }
        }
        if (lane == 63) out_score[b] = dp[7];
        return;
    }

    // ---------------- PV GEMM path ----------------
    const int bid = blockIdx.x - 16;
    const int n0 = (bid & 3) * 128;          // D/128 = 4
    const int m0 = ((bid >> 2) & 7) * 128;   // A/128 = 8
    const int bz = bid >> 5;                 // 16 batches
    const int K = V_DIM, N = D_DIM;

    const unsigned short* Ab = Pbf + (size_t)bz * A_DIM * V_DIM;
    const unsigned short* Bb = vTb + (size_t)bz * V_DIM * D_DIM;
    float*                Cb = out_aligned + (size_t)bz * A_DIM * D_DIM;

    const int tid = threadIdx.x, lane = tid & 63;
    const int w = tid >> 6, wy = w >> 1, wx = w & 1;
    const int u0 = tid, u1 = tid + 256;
    const int r_u0 = ((u0 >> 6) << 4) + (u0 & 15), k_u0 = ((u0 >> 4) & 3) * 8;
    const int r_u1 = ((u1 >> 6) << 4) + (u1 & 15), k_u1 = ((u1 >> 4) & 3) * 8;

    const unsigned short* gA0 = Ab + (size_t)(m0 + r_u0) * K + k_u0;
    const unsigned short* gA1 = Ab + (size_t)(m0 + r_u1) * K + k_u1;
    const unsigned short* gB0 = Bb + (size_t)(n0 + r_u0) * K + k_u0;
    const unsigned short* gB1 = Bb + (size_t)(n0 + r_u1) * K + k_u1;

    floatx4 acc[4][4];
    #pragma unroll
    for (int i = 0; i < 4; ++i)
        #pragma unroll
        for (int j = 0; j < 4; ++j) acc[i][j] = (floatx4){0.f, 0.f, 0.f, 0.f};

    bf16x8 a0 = *(const bf16x8*)(gA0);
    bf16x8 a1 = *(const bf16x8*)(gA1);
    bf16x8 b0 = *(const bf16x8*)(gB0);
    bf16x8 b1 = *(const bf16x8*)(gB1);

    for (int k0 = 0; k0 < K; k0 += 32) {
        __syncthreads();
        *(bf16x8*)&lA[(size_t)u0 * 8] = a0;
        *(bf16x8*)&lA[(size_t)u1 * 8] = a1;
        *(bf16x8*)&lB[(size_t)u0 * 8] = b0;
        *(bf16x8*)&lB[(size_t)u1 * 8] = b1;
        __syncthreads();
        if (k0 + 32 < K) {
            a0 = *(const bf16x8*)(gA0 + k0 + 32);
            a1 = *(const bf16x8*)(gA1 + k0 + 32);
            b0 = *(const bf16x8*)(gB0 + k0 + 32);
            b1 = *(const bf16x8*)(gB1 + k0 + 32);
        }
        bf16x8 fa[4], fb[4];
        #pragma unroll
        for (int t = 0; t < 4; ++t) {
            fa[t] = *(const bf16x8*)&lA[(((wy*4 + t)*64) + lane) * 8];
            fb[t] = *(const bf16x8*)&lB[(((wx*4 + t)*64) + lane) * 8];
        }
        #pragma unroll
        for (int i = 0; i < 4; ++i)
            #pragma unroll
            for (int j = 0; j < 4; ++j)
                acc[i][j] = __builtin_amdgcn_mfma_f32_16x16x32_bf16(fa[i], fb[j], acc[i][j], 0, 0, 0);
    }

    const int q = lane >> 4, c = lane & 15;
    #pragma unroll
    for (int i = 0; i < 4; ++i)
        #pragma unroll
        for (int j = 0; j < 4; ++j) {
            const int n = n0 + (wx*4 + j)*16 + c;
            #pragma unroll
            for (int r = 0; r < 4; ++r) {
                const int m = m0 + (wy*4 + i)*16 + q*4 + r;
                Cb[(size_t)m * N + n] = acc[i][j][r];
            }
        }
}

// ---------------------------------------------------------------------------
extern "C" void kernel_launch(void* const* d_in, const int* in_sizes, int n_in,
                              void* d_out, int out_size, void* d_ws, size_t ws_size,
                              hipStream_t stream)
{
    const float* audio = (const float*)d_in[0];   // [16,1024,512]
    const float* video = (const float*)d_in[1];   // [16, 512,512]
    const float* W     = (const float*)d_in[2];   // [512,512]
    const float* bias  = (const float*)d_in[3];   // [512]

    float* out_aligned = (float*)d_out;
    float* out_score   = (float*)d_out + (size_t)B_DIM * A_DIM * D_DIM;

    const size_t NA = (size_t)B_DIM * A_DIM * D_DIM;   // 8.39M
    const size_t NV = (size_t)B_DIM * V_DIM * D_DIM;   // 4.19M
    const size_t NS = (size_t)B_DIM * A_DIM * V_DIM;   // 8.39M

    float* ws = (float*)d_ws;
    float*          a_p  = ws;                                 // NA fp32
    float*          v_p  = a_p + NA;                           // NV fp32
    float*          sim  = v_p + NV;                           // NS fp32
    unsigned short* abf  = (unsigned short*)(sim + NS);        // NA bf16 [dead after proj-a]
    unsigned short* vbf  = (unsigned short*)(sim + NS) + NA;   // NV bf16 [dead after proj-v]
    unsigned short* v_nb = vbf + NV;                           // NV bf16
    unsigned short* Wbf  = v_nb + NV;                          // 262144 bf16
    unsigned short* a_nb = (unsigned short*)v_p;               // NA bf16 reuses v_p (NA/2 == NV floats)
    unsigned short* Pbf  = abf;                                // NS bf16 reuses dead abf
    unsigned short* vTb  = vbf;                                // NV bf16 reuses dead vbf

    // 1) fp32 -> bf16 input conversions
    cvt_bf16_kernel<<<dim3((int)(NA/8/256)), dim3(256), 0, stream>>>(audio, abf, (int)(NA/8));
    cvt_bf16_kernel<<<dim3((int)(NV/8/256)), dim3(256), 0, stream>>>(video, vbf, (int)(NV/8));
    cvt_bf16_kernel<<<dim3(D_DIM*D_DIM/8/256), dim3(256), 0, stream>>>(W, Wbf, D_DIM*D_DIM/8);

    // 2) projections: X @ W^T + b
    gemm_bf16_nt<<<dim3(D_DIM/128, (B_DIM*A_DIM)/128, 1), dim3(256), 0, stream>>>(
        abf, Wbf, bias, a_p, B_DIM*A_DIM, D_DIM, D_DIM, 0, 0, 0);
    gemm_bf16_nt<<<dim3(D_DIM/128, (B_DIM*V_DIM)/128, 1), dim3(256), 0, stream>>>(
        vbf, Wbf, bias, v_p, B_DIM*V_DIM, D_DIM, D_DIM, 0, 0, 0);

    // 3) normalize -> bf16 (v first: frees v_p for a_nb)
    rownorm_cvt_kernel<<<dim3((B_DIM*V_DIM)/4), dim3(256), 0, stream>>>(v_p, v_nb);
    rownorm_cvt_kernel<<<dim3((B_DIM*A_DIM)/4), dim3(256), 0, stream>>>(a_p, a_nb);

    // 4) sim[b] = a_n[b] @ v_n[b]^T
    gemm_bf16_nt<<<dim3(V_DIM/128, A_DIM/128, B_DIM), dim3(256), 0, stream>>>(
        a_nb, v_nb, nullptr, sim, A_DIM, V_DIM, D_DIM,
        (size_t)A_DIM*D_DIM, (size_t)V_DIM*D_DIM, (size_t)A_DIM*V_DIM);

    // 5) video -> vT bf16 (independent of sim)
    transpose_cvt_kernel<<<dim3(D_DIM/32, V_DIM/32, B_DIM), dim3(256), 0, stream>>>(video, vTb);

    // 6) fused row softmax -> Pbf + in-place prefix sum (sim becomes psum)
    softmax_psum_fused<<<dim3((B_DIM*A_DIM)/4), dim3(256), 0, stream>>>(sim, Pbf);

    // 7) fused PV GEMM + DTW (DTW blocks first so they start immediately)
    pv_dtw_kernel<<<dim3(16 + (D_DIM/128)*(A_DIM/128)*B_DIM), dim3(256), 0, stream>>>(
        Pbf, vTb, sim, out_aligned, out_score);
}